// Round 3
// baseline (238.985 us; speedup 1.0000x reference)
//
#include <hip/hip_runtime.h>
#include <cstdint>

#define BN_EPS 1e-5f

static constexpr int NB = 8192;
static constexpr int JLIN = 500;

// ---------------------------------------------------------------------------
// ws layout
//  h2b   [8192][128] u32  @ 0         4 MB   (row-major per sample)
//  h3    [8][8192]   u64  @ 4194304   512 KB (j-word plane major)
//  wlinT [128][512]  u32  @ 4718592   256 KB (k-major, j minor -> coalesced)
//  cdat  [64*10]     u32  @ 4980736          (9 masks + int threshold per ch)
//  lut   [512]       u32  @ 4983296
//  wout  [10*16]     u32  @ 4985344          (read as u64[8] per o)
//  Tlin  [512]       i32  @ 4985984
//  Bs    [8192]      i32  @ 4988032   32 KB
// ---------------------------------------------------------------------------

// ---------------------------------------------------------------------------
// pack kernel
//  blocks 0..124  : wlinT bit-packing (4 j-rows per block, ballot + regroup)
//  blocks 125..132: misc (lut 512 | cdat masks 576 | Tc2 64 | Tlin 512 | wout 160)
// ---------------------------------------------------------------------------
__global__ __launch_bounds__(256) void pack_kernel(
    const float* __restrict__ conv1_w, const float* __restrict__ conv1_b,
    const float* __restrict__ conv2_w, const float* __restrict__ conv2_b,
    const float* __restrict__ lin_w, const float* __restrict__ lin_b,
    const float* __restrict__ out_w,
    const float* __restrict__ bn1_g, const float* __restrict__ bn1_b,
    const float* __restrict__ bn1_m, const float* __restrict__ bn1_v,
    const float* __restrict__ bn2_g, const float* __restrict__ bn2_b,
    const float* __restrict__ bn2_m, const float* __restrict__ bn2_v,
    uint32_t* __restrict__ wlinT, uint32_t* __restrict__ cdat,
    uint32_t* __restrict__ lut, uint32_t* __restrict__ wout,
    int* __restrict__ Tlin)
{
    int tid = threadIdx.x;
    int b   = blockIdx.x;

    if (b < 125) {
        // ---- wlin packing for rows j = 4b .. 4b+3, stored transposed ----
        __shared__ uint32_t s_bm[4][122];   // row stride 488 B (8B aligned)
        int lane = tid & 63;
        int wv   = tid >> 6;
        for (int it = 0; it < 60; ++it) {
            int i = it * 256 + tid;                       // 0..15359
            float v = lin_w[(size_t)b * 15360 + i];
            uint64_t mask = __ballot(v > 0.0f);
            if (lane == 0) {
                int bi  = it * 256 + wv * 64;
                int row = bi / 3840;
                int f0  = bi % 3840;
                *((uint64_t*)&s_bm[row][f0 >> 5]) = mask;
            }
        }
        __syncthreads();
        for (int w = tid; w < 512; w += 256) {
            int row = w >> 7, k = w & 127;
            int c = k >> 1, hi = k & 1;
            int nb = hi ? 28 : 32;
            int f0 = c * 60 + hi * 32;
            uint32_t lo  = s_bm[row][f0 >> 5];
            uint32_t hiw = s_bm[row][(f0 >> 5) + 1];
            int sh = f0 & 31;
            uint32_t word = (uint32_t)((((uint64_t)hiw << 32) | lo) >> sh);
            if (nb < 32) word &= (1u << nb) - 1u;
            wlinT[(size_t)k * 512 + (b * 4 + row)] = word;
        }
        return;
    }

    int idx = (b - 125) * 256 + tid;     // 0..2047
    if (idx < 512) {
        // conv1 LUT: exact reference epilogue per 9-bit sign pattern
        uint32_t px = (uint32_t)idx;
        uint32_t word = 0;
        for (int c = 0; c < 32; ++c) {
            uint32_t wp = 0;
            for (int t = 0; t < 9; ++t)
                wp |= (conv1_w[c * 9 + t] < 0.0f ? 1u : 0u) << t;
            int d = 9 - 2 * __popc(px ^ wp);
            float inv = bn1_g[c] / sqrtf(bn1_v[c] + BN_EPS);
            float sh  = bn1_b[c] - bn1_m[c] * inv;
            float z = __fadd_rn((float)d, conv1_b[c]);
            z = __fadd_rn(__fmul_rn(z, inv), sh);
            word |= (z > 0.0f ? 1u : 0u) << c;
        }
        lut[idx] = word;
    } else if (idx < 512 + 576) {
        // conv2 masks (complemented when inv < 0 so bit = (v >= T) uniformly)
        int t = idx - 512;
        int c = t / 9, tap = t % 9;
        uint32_t w = 0;
        for (int ic = 0; ic < 32; ++ic)
            w |= (conv2_w[c * 288 + ic * 9 + tap] > 0.0f ? 1u : 0u) << ic;
        float inv = bn2_g[c] / sqrtf(bn2_v[c] + BN_EPS);
        if (inv < 0.0f) w = ~w;
        cdat[c * 10 + tap] = w;
    } else if (idx < 512 + 576 + 64) {
        // conv2 integer thresholds: exact monotone scan of reference epilogue
        int c = idx - (512 + 576);
        float inv = bn2_g[c] / sqrtf(bn2_v[c] + BN_EPS);
        float sh  = bn2_b[c] - bn2_m[c] * inv;
        float b2  = conv2_b[c];
        int T = 10000;
        for (int u = -300; u <= 300; ++u) {
            float v = (inv < 0.0f) ? (float)(-u) : (float)u;
            float z = __fadd_rn(__fmul_rn(__fadd_rn(v, b2), inv), sh);
            if (z > 0.0f) { T = u; break; }
        }
        cdat[c * 10 + 9] = (uint32_t)T;
    } else if (idx < 512 + 576 + 64 + 512) {
        // lin integer thresholds
        int j = idx - (512 + 576 + 64);
        int T = 10000;
        if (j < JLIN) {
            float lb = lin_b[j];
            int base = (int)floorf(-lb) - 2;
            for (int u = base; u <= base + 5; ++u)
                if (__fadd_rn((float)u, lb) > 0.0f) { T = u; break; }
        }
        Tlin[j] = T;
    } else if (idx < 512 + 576 + 64 + 512 + 160) {
        int t = idx - (512 + 576 + 64 + 512);
        int j = t >> 4, k = t & 15;
        uint32_t w = 0;
        for (int bb = 0; bb < 32; ++bb) {
            int jj = k * 32 + bb;
            if (jj < JLIN) w |= (out_w[j * 500 + jj] > 0.0f ? 1u : 0u) << bb;
        }
        wout[t] = w;
    }
}

// ---------------------------------------------------------------------------
// conv kernel: 4 samples/block, 2048 blocks (8 blocks/CU -> full occupancy).
//  phase 1: ballot-pack x sign bits (wave = sample)
//  phase 2: conv1 via LUT -> s_in packed words
//  phase 3: conv2, lane = position, 64-ch loop with 1 scalar row load/ch,
//           integer-threshold epilogue, ballot pack; also per-sample B sum.
// output h2b row-major [s][128] so lin can scalar-load activation rows.
// ---------------------------------------------------------------------------
__global__ __launch_bounds__(256) void conv_kernel(
    const float* __restrict__ x,
    const uint32_t* __restrict__ cdat,
    const uint32_t* __restrict__ lut,
    uint32_t* __restrict__ h2b, int* __restrict__ Bs)
{
    __shared__ uint64_t s_rows[4][24];
    __shared__ uint32_t s_lut[512];
    __shared__ uint32_t s_in[4][288];    // 286 used

    int tid  = threadIdx.x;
    int lane = tid & 63;
    int wv   = tid >> 6;
    int s    = blockIdx.x * 4 + wv;

    s_lut[tid]       = lut[tid];
    s_lut[tid + 256] = lut[tid + 256];

    // phase 1: wave wv packs sample s's sign bitmap rows
    const float* xs = x + (size_t)s * 1296;
    for (int r = 0; r < 24; ++r) {
        float v = (lane < 54) ? xs[r * 54 + lane] : 1.0f;
        uint64_t mk = __ballot(v < 0.0f);
        if (lane == 0) s_rows[wv][r] = mk;
    }
    __syncthreads();

    // phase 2: conv1 via LUT
    for (int i = tid; i < 4 * 286; i += 256) {
        int sl = i / 286, p = i - sl * 286;
        int oy = p / 26, ox = p - oy * 26;
        uint64_t r0 = s_rows[sl][2 * oy];
        uint64_t r1 = s_rows[sl][2 * oy + 1];
        uint64_t r2 = s_rows[sl][2 * oy + 2];
        int sh = 2 * ox;
        uint32_t px = ((uint32_t)(r0 >> sh) & 7u)
                    | (((uint32_t)(r1 >> sh) & 7u) << 3)
                    | (((uint32_t)(r2 >> sh) & 7u) << 6);
        s_in[sl][p] = s_lut[px];
    }
    __syncthreads();

    // phase 3: wave wv -> sample s; lane = output position
    int p  = (lane < 60) ? lane : 59;
    int oy = p / 12, ox = p - 12 * oy;
    uint32_t t[9];
    #pragma unroll
    for (int ky = 0; ky < 3; ++ky) {
        const uint32_t* rp = &s_in[wv][(2 * oy + ky) * 26 + 2 * ox];
        t[ky * 3 + 0] = rp[0];
        t[ky * 3 + 1] = rp[1];
        t[ky * 3 + 2] = rp[2];
    }
    int B = 0;
    #pragma unroll
    for (int q = 0; q < 9; ++q) B += __popc(t[q]);
    int nB = -B;

    uint32_t w0 = 0, w1 = 0;
    for (int c = 0; c < 64; ++c) {
        const uint32_t* cd = cdat + c * 10;   // wave-uniform -> s_load
        int P = 0;
        #pragma unroll
        for (int q = 0; q < 9; ++q) P += __popc(t[q] & cd[q]);
        int v = 2 * P + nB;
        uint64_t mk = __ballot(v >= (int)cd[9]);
        if (lane == c) {
            w0 = (uint32_t)mk;
            w1 = (uint32_t)(mk >> 32) & 0x0FFFFFFFu;   // drop dup lanes 60..63
        }
    }

    // per-sample total bit count for the lin layer (wave reduce)
    int bsum = __popc(w0) + __popc(w1);
    #pragma unroll
    for (int off = 32; off > 0; off >>= 1) bsum += __shfl_xor(bsum, off, 64);
    if (lane == 0) Bs[s] = bsum;

    // lane c owns channel c's two words; row-major store, coalesced
    *(uint2*)(h2b + (size_t)s * 128 + 2 * lane) = make_uint2(w0, w1);
}

// ---------------------------------------------------------------------------
// lin kernel: lane = j (wave covers 64 j), acts via wave-uniform scalar loads.
// wlinT row held in 128 VGPRs (launch_bounds(256,3) -> ~170 VGPR budget).
// wave-task = (jw 0..7, chunk of 16 samples); 4096 waves.
// ---------------------------------------------------------------------------
__global__ __launch_bounds__(256, 3) void lin_kernel(
    const uint32_t* __restrict__ h2b,
    const uint32_t* __restrict__ wlinT,
    const int* __restrict__ Tlin,
    const int* __restrict__ Bs,
    uint64_t* __restrict__ h3)
{
    int lane = threadIdx.x & 63;
    int wv   = __builtin_amdgcn_readfirstlane((int)(threadIdx.x >> 6));
    int g    = blockIdx.x * 4 + wv;      // 0..4095
    int jw    = g & 7;
    int chunk = g >> 3;                  // 0..511
    int j     = jw * 64 + lane;

    uint32_t w[128];
    #pragma unroll
    for (int k = 0; k < 128; ++k) w[k] = wlinT[(size_t)k * 512 + j];
    int T = Tlin[j];

    int sbase = chunk * 16;
    for (int i = 0; i < 16; ++i) {
        int s = sbase + i;
        const uint32_t* ar = h2b + (size_t)s * 128;   // uniform -> s_load
        int P = 0;
        #pragma unroll
        for (int k = 0; k < 128; ++k) P += __popc(ar[k] & w[k]);
        int v = 2 * P - Bs[s];
        uint64_t mk = __ballot(v >= T);
        if (lane == 0) h3[(size_t)jw * NB + s] = mk;
    }
}

// ---------------------------------------------------------------------------
// out kernel: thread -> (o, s); o uniform per block -> wout scalar loads.
// ---------------------------------------------------------------------------
__global__ __launch_bounds__(256) void out_kernel(
    const uint64_t* __restrict__ h3,
    const uint32_t* __restrict__ wout,
    const float* __restrict__ out_b,
    float* __restrict__ out)
{
    int gidx = blockIdx.x * 256 + threadIdx.x;   // 0..81919
    int o = gidx >> 13;
    int s = gidx & 8191;
    const uint64_t* wo = (const uint64_t*)wout + o * 8;
    int P = 0, B = 0;
    #pragma unroll
    for (int k = 0; k < 8; ++k) {
        uint64_t a = h3[(size_t)k * NB + s];
        P += __popcll(a & wo[k]);
        B += __popcll(a);
    }
    out[(size_t)s * 10 + o] = __fadd_rn((float)(2 * P - B), out_b[o]);
}

// ---------------------------------------------------------------------------
extern "C" void kernel_launch(void* const* d_in, const int* in_sizes, int n_in,
                              void* d_out, int out_size, void* d_ws, size_t ws_size,
                              hipStream_t stream)
{
    const float* x       = (const float*)d_in[0];
    const float* conv1_w = (const float*)d_in[1];
    const float* conv1_b = (const float*)d_in[2];
    const float* bn1_g   = (const float*)d_in[3];
    const float* bn1_b   = (const float*)d_in[4];
    const float* bn1_m   = (const float*)d_in[5];
    const float* bn1_v   = (const float*)d_in[6];
    const float* conv2_w = (const float*)d_in[7];
    const float* conv2_b = (const float*)d_in[8];
    const float* bn2_g   = (const float*)d_in[9];
    const float* bn2_b   = (const float*)d_in[10];
    const float* bn2_m   = (const float*)d_in[11];
    const float* bn2_v   = (const float*)d_in[12];
    const float* lin_w   = (const float*)d_in[13];
    const float* lin_b   = (const float*)d_in[14];
    const float* out_w   = (const float*)d_in[15];
    const float* out_b   = (const float*)d_in[16];

    char* ws = (char*)d_ws;
    uint32_t* h2b   = (uint32_t*)(ws + 0);
    uint64_t* h3    = (uint64_t*)(ws + 4194304);
    uint32_t* wlinT = (uint32_t*)(ws + 4718592);
    uint32_t* cdat  = (uint32_t*)(ws + 4980736);
    uint32_t* lut   = (uint32_t*)(ws + 4983296);
    uint32_t* wout  = (uint32_t*)(ws + 4985344);
    int*      Tlin  = (int*)     (ws + 4985984);
    int*      Bs    = (int*)     (ws + 4988032);

    pack_kernel<<<133, 256, 0, stream>>>(conv1_w, conv1_b, conv2_w, conv2_b,
                                         lin_w, lin_b, out_w,
                                         bn1_g, bn1_b, bn1_m, bn1_v,
                                         bn2_g, bn2_b, bn2_m, bn2_v,
                                         wlinT, cdat, lut, wout, Tlin);
    conv_kernel<<<NB / 4, 256, 0, stream>>>(x, cdat, lut, h2b, Bs);
    lin_kernel<<<1024, 256, 0, stream>>>(h2b, wlinT, Tlin, Bs, h3);
    out_kernel<<<320, 256, 0, stream>>>(h3, wout, out_b, (float*)d_out);
}

// Round 5
// 202.926 us; speedup vs baseline: 1.1777x; 1.1777x over previous
//
#include <hip/hip_runtime.h>
#include <cstdint>

#define BN_EPS 1e-5f

static constexpr int NB = 8192;
static constexpr int JLIN = 500;

// ---------------------------------------------------------------------------
// ws layout
//  h2b   [8192][128] u32   @ 0         4 MB   (row-major per sample)
//  h3    [8][8192]   u64   @ 4194304   512 KB (j-word plane major)
//  wlin4 [8][32][64][4] u32 @ 4718592  256 KB (per-jw LDS image: kq, j, q)
//  cdat  [64*10]     u32   @ 4980736          (9 masks + int threshold per ch)
//  lut   [512]       u32   @ 4983296
//  wout  [10*16]     u32   @ 4985344          (read as u64[8] per o)
//  Tlin  [512]       i32   @ 4985984
//  Bs    [8192]      i32   @ 4988032   32 KB
// ---------------------------------------------------------------------------

// ---------------------------------------------------------------------------
// pack kernel, grid = 508 blocks:
//  blocks 0..499  : wlin row j = blockIdx (15-iter ballot chain) -> wlin4
//  blocks 500..501: conv1 LUT (LDS-staged weights/BN)
//  blocks 502..507: cdat masks | Tc2 | Tlin | wout
// ---------------------------------------------------------------------------
__global__ __launch_bounds__(256) void pack_kernel(
    const float* __restrict__ conv1_w, const float* __restrict__ conv1_b,
    const float* __restrict__ conv2_w, const float* __restrict__ conv2_b,
    const float* __restrict__ lin_w, const float* __restrict__ lin_b,
    const float* __restrict__ out_w,
    const float* __restrict__ bn1_g, const float* __restrict__ bn1_b,
    const float* __restrict__ bn1_m, const float* __restrict__ bn1_v,
    const float* __restrict__ bn2_g, const float* __restrict__ bn2_b,
    const float* __restrict__ bn2_m, const float* __restrict__ bn2_v,
    uint32_t* __restrict__ wlin4, uint32_t* __restrict__ cdat,
    uint32_t* __restrict__ lut, uint32_t* __restrict__ wout,
    int* __restrict__ Tlin)
{
    __shared__ uint32_t s_bm[122];
    __shared__ float    s_c1w[288];
    __shared__ uint32_t s_wp[32];
    __shared__ float    s_inv1[32], s_sh1[32], s_b1[32];

    int tid  = threadIdx.x;
    int lane = tid & 63;
    int wv   = tid >> 6;
    int b    = blockIdx.x;

    if (b < 500) {
        // ---- one lin_w row -> 128 packed k-words -> wlin4 scatter ----
        int j = b;
        if (tid == 0) { s_bm[120] = 0; s_bm[121] = 0; }
        for (int it = 0; it < 15; ++it) {
            int i = it * 256 + tid;                   // 0..3839
            float v = lin_w[(size_t)j * 3840 + i];
            uint64_t mask = __ballot(v > 0.0f);
            if (lane == 0)
                *((uint64_t*)&s_bm[(it * 256 + wv * 64) >> 5]) = mask;
        }
        __syncthreads();
        if (tid < 128) {
            int k = tid;
            int c = k >> 1, hi = k & 1;
            int nb = hi ? 28 : 32;
            int f0 = c * 60 + hi * 32;
            uint32_t lo  = s_bm[f0 >> 5];
            uint32_t hiw = s_bm[(f0 >> 5) + 1];
            int sh = f0 & 31;
            uint32_t word = (uint32_t)((((uint64_t)hiw << 32) | lo) >> sh);
            if (nb < 32) word &= (1u << nb) - 1u;
            int jw = j >> 6, jl = j & 63, kq = k >> 2, q = k & 3;
            wlin4[jw * 8192 + kq * 256 + jl * 4 + q] = word;
        }
        return;
    }

    int mb = b - 500;
    if (mb < 2) {
        // ---- conv1 LUT, LDS-staged (grid-stride: 288 > 256 threads!) ----
        for (int i = tid; i < 288; i += 256) s_c1w[i] = conv1_w[i];
        __syncthreads();
        if (tid < 32) {
            uint32_t wp = 0;
            for (int t = 0; t < 9; ++t)
                wp |= (s_c1w[tid * 9 + t] < 0.0f ? 1u : 0u) << t;
            s_wp[tid] = wp;
            float inv = bn1_g[tid] / sqrtf(bn1_v[tid] + BN_EPS);
            s_inv1[tid] = inv;
            s_sh1[tid]  = bn1_b[tid] - bn1_m[tid] * inv;
            s_b1[tid]   = conv1_b[tid];
        }
        __syncthreads();
        uint32_t px = (uint32_t)(mb * 256 + tid);     // 0..511
        uint32_t word = 0;
        for (int c = 0; c < 32; ++c) {
            int d = 9 - 2 * __popc(px ^ s_wp[c]);
            float z = __fadd_rn((float)d, s_b1[c]);
            z = __fadd_rn(__fmul_rn(z, s_inv1[c]), s_sh1[c]);
            word |= (z > 0.0f ? 1u : 0u) << c;
        }
        lut[px] = word;
        return;
    }

    int idx = (mb - 2) * 256 + tid;     // 0..1535
    if (idx < 576) {
        // conv2 masks (complemented when inv < 0 so bit = (v >= T) uniformly)
        int c = idx / 9, tap = idx % 9;
        uint32_t w = 0;
        for (int ic = 0; ic < 32; ++ic)
            w |= (conv2_w[c * 288 + ic * 9 + tap] > 0.0f ? 1u : 0u) << ic;
        float inv = bn2_g[c] / sqrtf(bn2_v[c] + BN_EPS);
        if (inv < 0.0f) w = ~w;
        cdat[c * 10 + tap] = w;
    } else if (idx < 576 + 64) {
        // conv2 integer thresholds: exact monotone scan of reference epilogue
        int c = idx - 576;
        float inv = bn2_g[c] / sqrtf(bn2_v[c] + BN_EPS);
        float sh  = bn2_b[c] - bn2_m[c] * inv;
        float b2  = conv2_b[c];
        int T = 10000;
        for (int u = -300; u <= 300; ++u) {
            float v = (inv < 0.0f) ? (float)(-u) : (float)u;
            float z = __fadd_rn(__fmul_rn(__fadd_rn(v, b2), inv), sh);
            if (z > 0.0f) { T = u; break; }
        }
        cdat[c * 10 + 9] = (uint32_t)T;
    } else if (idx < 576 + 64 + 512) {
        // lin integer thresholds
        int j = idx - (576 + 64);
        int T = 10000;
        if (j < JLIN) {
            float lb = lin_b[j];
            int base = (int)floorf(-lb) - 2;
            for (int u = base; u <= base + 5; ++u)
                if (__fadd_rn((float)u, lb) > 0.0f) { T = u; break; }
        }
        Tlin[j] = T;
    } else if (idx < 576 + 64 + 512 + 160) {
        int t = idx - (576 + 64 + 512);
        int j = t >> 4, k = t & 15;
        uint32_t w = 0;
        for (int bb = 0; bb < 32; ++bb) {
            int jj = k * 32 + bb;
            if (jj < JLIN) w |= (out_w[j * 500 + jj] > 0.0f ? 1u : 0u) << bb;
        }
        wout[t] = w;
    }
}

// ---------------------------------------------------------------------------
// conv kernel: 4 samples/block, 2048 blocks.
// ---------------------------------------------------------------------------
__global__ __launch_bounds__(256) void conv_kernel(
    const float* __restrict__ x,
    const uint32_t* __restrict__ cdat,
    const uint32_t* __restrict__ lut,
    uint32_t* __restrict__ h2b, int* __restrict__ Bs)
{
    __shared__ uint64_t s_rows[4][24];
    __shared__ uint32_t s_lut[512];
    __shared__ uint32_t s_in[4][288];    // 286 used

    int tid  = threadIdx.x;
    int lane = tid & 63;
    int wv   = tid >> 6;
    int s    = blockIdx.x * 4 + wv;

    s_lut[tid]       = lut[tid];
    s_lut[tid + 256] = lut[tid + 256];

    // phase 1: wave wv packs sample s's sign bitmap rows
    const float* xs = x + (size_t)s * 1296;
    for (int r = 0; r < 24; ++r) {
        float v = (lane < 54) ? xs[r * 54 + lane] : 1.0f;
        uint64_t mk = __ballot(v < 0.0f);
        if (lane == 0) s_rows[wv][r] = mk;
    }
    __syncthreads();

    // phase 2: conv1 via LUT
    for (int i = tid; i < 4 * 286; i += 256) {
        int sl = i / 286, p = i - sl * 286;
        int oy = p / 26, ox = p - oy * 26;
        uint64_t r0 = s_rows[sl][2 * oy];
        uint64_t r1 = s_rows[sl][2 * oy + 1];
        uint64_t r2 = s_rows[sl][2 * oy + 2];
        int sh = 2 * ox;
        uint32_t px = ((uint32_t)(r0 >> sh) & 7u)
                    | (((uint32_t)(r1 >> sh) & 7u) << 3)
                    | (((uint32_t)(r2 >> sh) & 7u) << 6);
        s_in[sl][p] = s_lut[px];
    }
    __syncthreads();

    // phase 3: wave wv -> sample s; lane = output position
    int p  = (lane < 60) ? lane : 59;
    int oy = p / 12, ox = p - 12 * oy;
    uint32_t t[9];
    #pragma unroll
    for (int ky = 0; ky < 3; ++ky) {
        const uint32_t* rp = &s_in[wv][(2 * oy + ky) * 26 + 2 * ox];
        t[ky * 3 + 0] = rp[0];
        t[ky * 3 + 1] = rp[1];
        t[ky * 3 + 2] = rp[2];
    }
    int B = 0;
    #pragma unroll
    for (int q = 0; q < 9; ++q) B += __popc(t[q]);
    int nB = -B;

    uint32_t w0 = 0, w1 = 0;
    for (int c = 0; c < 64; ++c) {
        const uint32_t* cd = cdat + c * 10;   // wave-uniform -> s_load
        int P = 0;
        #pragma unroll
        for (int q = 0; q < 9; ++q) P += __popc(t[q] & cd[q]);
        int v = 2 * P + nB;
        uint64_t mk = __ballot(v >= (int)cd[9]);
        if (lane == c) {
            w0 = (uint32_t)mk;
            w1 = (uint32_t)(mk >> 32) & 0x0FFFFFFFu;   // drop dup lanes 60..63
        }
    }

    int bsum = __popc(w0) + __popc(w1);
    #pragma unroll
    for (int off = 32; off > 0; off >>= 1) bsum += __shfl_xor(bsum, off, 64);
    if (lane == 0) Bs[s] = bsum;

    *(uint2*)(h2b + (size_t)s * 128 + 2 * lane) = make_uint2(w0, w1);
}

// ---------------------------------------------------------------------------
// lin kernel: weight tile in LDS (32 KB, prebuilt layout), lane = j.
// Activations via wave-uniform s_load_dwordx4; 16 samples/wave.
// grid: 1024 blocks = 8 jw x 128 chunks; block = 4 waves x 16 samples.
// ---------------------------------------------------------------------------
__global__ __launch_bounds__(256) void lin_kernel(
    const uint32_t* __restrict__ h2b,
    const uint32_t* __restrict__ wlin4,
    const int* __restrict__ Tlin,
    const int* __restrict__ Bs,
    uint64_t* __restrict__ h3)
{
    __shared__ uint4 s_w[2048];          // [kq*64 + j] : 32 KB

    int tid  = threadIdx.x;
    int lane = tid & 63;
    int wv   = __builtin_amdgcn_readfirstlane((int)(tid >> 6));
    int jw    = blockIdx.x & 7;
    int chunk = blockIdx.x >> 3;         // 0..127

    const uint4* wsrc = (const uint4*)wlin4 + (size_t)jw * 2048;
    #pragma unroll
    for (int i = 0; i < 8; ++i)
        s_w[i * 256 + tid] = wsrc[i * 256 + tid];

    int j = jw * 64 + lane;
    int T = Tlin[j];
    int sbase = chunk * 64 + wv * 16;
    __syncthreads();

    int P[16];
    #pragma unroll
    for (int i = 0; i < 16; ++i) P[i] = 0;

    for (int kq = 0; kq < 32; ++kq) {
        uint4 w4 = s_w[kq * 64 + lane];
        const uint4* abase = (const uint4*)(h2b + (size_t)sbase * 128) + kq;
        #pragma unroll
        for (int i = 0; i < 16; ++i) {
            uint4 a = abase[i * 32];                 // wave-uniform -> s_load
            P[i] += __popc(a.x & w4.x);
            P[i] += __popc(a.y & w4.y);
            P[i] += __popc(a.z & w4.z);
            P[i] += __popc(a.w & w4.w);
        }
    }

    #pragma unroll
    for (int i = 0; i < 16; ++i) {
        int s = sbase + i;
        int v = 2 * P[i] - Bs[s];
        uint64_t mk = __ballot(v >= T);
        if (lane == 0) h3[(size_t)jw * NB + s] = mk;
    }
}

// ---------------------------------------------------------------------------
// out kernel: thread -> (o, s); o uniform per block -> wout scalar loads.
// ---------------------------------------------------------------------------
__global__ __launch_bounds__(256) void out_kernel(
    const uint64_t* __restrict__ h3,
    const uint32_t* __restrict__ wout,
    const float* __restrict__ out_b,
    float* __restrict__ out)
{
    int gidx = blockIdx.x * 256 + threadIdx.x;   // 0..81919
    int o = gidx >> 13;
    int s = gidx & 8191;
    const uint64_t* wo = (const uint64_t*)wout + o * 8;
    int P = 0, B = 0;
    #pragma unroll
    for (int k = 0; k < 8; ++k) {
        uint64_t a = h3[(size_t)k * NB + s];
        P += __popcll(a & wo[k]);
        B += __popcll(a);
    }
    out[(size_t)s * 10 + o] = __fadd_rn((float)(2 * P - B), out_b[o]);
}

// ---------------------------------------------------------------------------
extern "C" void kernel_launch(void* const* d_in, const int* in_sizes, int n_in,
                              void* d_out, int out_size, void* d_ws, size_t ws_size,
                              hipStream_t stream)
{
    const float* x       = (const float*)d_in[0];
    const float* conv1_w = (const float*)d_in[1];
    const float* conv1_b = (const float*)d_in[2];
    const float* bn1_g   = (const float*)d_in[3];
    const float* bn1_b   = (const float*)d_in[4];
    const float* bn1_m   = (const float*)d_in[5];
    const float* bn1_v   = (const float*)d_in[6];
    const float* conv2_w = (const float*)d_in[7];
    const float* conv2_b = (const float*)d_in[8];
    const float* bn2_g   = (const float*)d_in[9];
    const float* bn2_b   = (const float*)d_in[10];
    const float* bn2_m   = (const float*)d_in[11];
    const float* bn2_v   = (const float*)d_in[12];
    const float* lin_w   = (const float*)d_in[13];
    const float* lin_b   = (const float*)d_in[14];
    const float* out_w   = (const float*)d_in[15];
    const float* out_b   = (const float*)d_in[16];

    char* ws = (char*)d_ws;
    uint32_t* h2b   = (uint32_t*)(ws + 0);
    uint64_t* h3    = (uint64_t*)(ws + 4194304);
    uint32_t* wlin4 = (uint32_t*)(ws + 4718592);
    uint32_t* cdat  = (uint32_t*)(ws + 4980736);
    uint32_t* lut   = (uint32_t*)(ws + 4983296);
    uint32_t* wout  = (uint32_t*)(ws + 4985344);
    int*      Tlin  = (int*)     (ws + 4985984);
    int*      Bs    = (int*)     (ws + 4988032);

    pack_kernel<<<508, 256, 0, stream>>>(conv1_w, conv1_b, conv2_w, conv2_b,
                                         lin_w, lin_b, out_w,
                                         bn1_g, bn1_b, bn1_m, bn1_v,
                                         bn2_g, bn2_b, bn2_m, bn2_v,
                                         wlin4, cdat, lut, wout, Tlin);
    conv_kernel<<<NB / 4, 256, 0, stream>>>(x, cdat, lut, h2b, Bs);
    lin_kernel<<<1024, 256, 0, stream>>>(h2b, wlin4, Tlin, Bs, h3);
    out_kernel<<<320, 256, 0, stream>>>(h3, wout, out_b, (float*)d_out);
}

// Round 6
// 198.992 us; speedup vs baseline: 1.2010x; 1.0198x over previous
//
#include <hip/hip_runtime.h>
#include <cstdint>

#define BN_EPS 1e-5f

static constexpr int NB = 8192;
static constexpr int JLIN = 500;

// ---------------------------------------------------------------------------
// ws layout
//  h2b   [8192][128] u32   @ 0         4 MB   (row-major per sample)
//  h3    [8][8192]   u64   @ 4194304   512 KB (j-word plane major)
//  wlin4 [8][32][64][4] u32 @ 4718592  256 KB (per-jw LDS image: kq, j, q)
//  cdat  [64*10]     u32   @ 4980736          (9 masks + int threshold per ch)
//  lut   [512]       u32   @ 4983296
//  wout  [10*16]     u32   @ 4985344          (read as u64[8] per o)
//  Tlin  [512]       i32   @ 4985984
//  Bs    [8192]      i32   @ 4988032   32 KB
// ---------------------------------------------------------------------------

// ---------------------------------------------------------------------------
// pack kernel, grid = 508 blocks:
//  blocks 0..499  : wlin row j = blockIdx (15-iter ballot chain) -> wlin4
//  blocks 500..501: conv1 LUT (LDS-staged weights/BN)
//  blocks 502..507: cdat masks | Tc2 | Tlin | wout
// ---------------------------------------------------------------------------
__global__ __launch_bounds__(256) void pack_kernel(
    const float* __restrict__ conv1_w, const float* __restrict__ conv1_b,
    const float* __restrict__ conv2_w, const float* __restrict__ conv2_b,
    const float* __restrict__ lin_w, const float* __restrict__ lin_b,
    const float* __restrict__ out_w,
    const float* __restrict__ bn1_g, const float* __restrict__ bn1_b,
    const float* __restrict__ bn1_m, const float* __restrict__ bn1_v,
    const float* __restrict__ bn2_g, const float* __restrict__ bn2_b,
    const float* __restrict__ bn2_m, const float* __restrict__ bn2_v,
    uint32_t* __restrict__ wlin4, uint32_t* __restrict__ cdat,
    uint32_t* __restrict__ lut, uint32_t* __restrict__ wout,
    int* __restrict__ Tlin)
{
    __shared__ uint32_t s_bm[122];
    __shared__ float    s_c1w[288];
    __shared__ uint32_t s_wp[32];
    __shared__ float    s_inv1[32], s_sh1[32], s_b1[32];

    int tid  = threadIdx.x;
    int lane = tid & 63;
    int wv   = tid >> 6;
    int b    = blockIdx.x;

    if (b < 500) {
        // ---- one lin_w row -> 128 packed k-words -> wlin4 scatter ----
        int j = b;
        if (tid == 0) { s_bm[120] = 0; s_bm[121] = 0; }
        for (int it = 0; it < 15; ++it) {
            int i = it * 256 + tid;                   // 0..3839
            float v = lin_w[(size_t)j * 3840 + i];
            uint64_t mask = __ballot(v > 0.0f);
            if (lane == 0)
                *((uint64_t*)&s_bm[(it * 256 + wv * 64) >> 5]) = mask;
        }
        __syncthreads();
        if (tid < 128) {
            int k = tid;
            int c = k >> 1, hi = k & 1;
            int nb = hi ? 28 : 32;
            int f0 = c * 60 + hi * 32;
            uint32_t lo  = s_bm[f0 >> 5];
            uint32_t hiw = s_bm[(f0 >> 5) + 1];
            int sh = f0 & 31;
            uint32_t word = (uint32_t)((((uint64_t)hiw << 32) | lo) >> sh);
            if (nb < 32) word &= (1u << nb) - 1u;
            int jw = j >> 6, jl = j & 63, kq = k >> 2, q = k & 3;
            wlin4[jw * 8192 + kq * 256 + jl * 4 + q] = word;
        }
        return;
    }

    int mb = b - 500;
    if (mb < 2) {
        // ---- conv1 LUT, LDS-staged (grid-stride: 288 > 256 threads) ----
        for (int i = tid; i < 288; i += 256) s_c1w[i] = conv1_w[i];
        __syncthreads();
        if (tid < 32) {
            uint32_t wp = 0;
            for (int t = 0; t < 9; ++t)
                wp |= (s_c1w[tid * 9 + t] < 0.0f ? 1u : 0u) << t;
            s_wp[tid] = wp;
            float inv = bn1_g[tid] / sqrtf(bn1_v[tid] + BN_EPS);
            s_inv1[tid] = inv;
            s_sh1[tid]  = bn1_b[tid] - bn1_m[tid] * inv;
            s_b1[tid]   = conv1_b[tid];
        }
        __syncthreads();
        uint32_t px = (uint32_t)(mb * 256 + tid);     // 0..511
        uint32_t word = 0;
        for (int c = 0; c < 32; ++c) {
            int d = 9 - 2 * __popc(px ^ s_wp[c]);
            float z = __fadd_rn((float)d, s_b1[c]);
            z = __fadd_rn(__fmul_rn(z, s_inv1[c]), s_sh1[c]);
            word |= (z > 0.0f ? 1u : 0u) << c;
        }
        lut[px] = word;
        return;
    }

    int idx = (mb - 2) * 256 + tid;     // 0..1535
    if (idx < 576) {
        // conv2 masks (complemented when inv < 0 so bit = (v >= T) uniformly)
        int c = idx / 9, tap = idx % 9;
        uint32_t w = 0;
        for (int ic = 0; ic < 32; ++ic)
            w |= (conv2_w[c * 288 + ic * 9 + tap] > 0.0f ? 1u : 0u) << ic;
        float inv = bn2_g[c] / sqrtf(bn2_v[c] + BN_EPS);
        if (inv < 0.0f) w = ~w;
        cdat[c * 10 + tap] = w;
    } else if (idx < 576 + 64) {
        // conv2 integer thresholds: exact monotone scan of reference epilogue
        int c = idx - 576;
        float inv = bn2_g[c] / sqrtf(bn2_v[c] + BN_EPS);
        float sh  = bn2_b[c] - bn2_m[c] * inv;
        float b2  = conv2_b[c];
        int T = 10000;
        for (int u = -300; u <= 300; ++u) {
            float v = (inv < 0.0f) ? (float)(-u) : (float)u;
            float z = __fadd_rn(__fmul_rn(__fadd_rn(v, b2), inv), sh);
            if (z > 0.0f) { T = u; break; }
        }
        cdat[c * 10 + 9] = (uint32_t)T;
    } else if (idx < 576 + 64 + 512) {
        // lin integer thresholds
        int j = idx - (576 + 64);
        int T = 10000;
        if (j < JLIN) {
            float lb = lin_b[j];
            int base = (int)floorf(-lb) - 2;
            for (int u = base; u <= base + 5; ++u)
                if (__fadd_rn((float)u, lb) > 0.0f) { T = u; break; }
        }
        Tlin[j] = T;
    } else if (idx < 576 + 64 + 512 + 160) {
        int t = idx - (576 + 64 + 512);
        int j = t >> 4, k = t & 15;
        uint32_t w = 0;
        for (int bb = 0; bb < 32; ++bb) {
            int jj = k * 32 + bb;
            if (jj < JLIN) w |= (out_w[j * 500 + jj] > 0.0f ? 1u : 0u) << bb;
        }
        wout[t] = w;
    }
}

// ---------------------------------------------------------------------------
// conv kernel: 4 samples/block, 2048 blocks.
// launch_bounds(256,6): cap VGPR ~85 so 6 waves/SIMD can be resident
// (R5 ran at 124 VGPR -> 4 waves/SIMD -> 35% occupancy, latency-bound).
// ---------------------------------------------------------------------------
__global__ __launch_bounds__(256, 6) void conv_kernel(
    const float* __restrict__ x,
    const uint32_t* __restrict__ cdat,
    const uint32_t* __restrict__ lut,
    uint32_t* __restrict__ h2b, int* __restrict__ Bs)
{
    __shared__ uint64_t s_rows[4][24];
    __shared__ uint32_t s_lut[512];
    __shared__ uint32_t s_in[4][288];    // 286 used

    int tid  = threadIdx.x;
    int lane = tid & 63;
    int wv   = tid >> 6;
    int s    = blockIdx.x * 4 + wv;

    s_lut[tid]       = lut[tid];
    s_lut[tid + 256] = lut[tid + 256];

    // phase 1: wave wv packs sample s's sign bitmap rows
    const float* xs = x + (size_t)s * 1296;
    for (int r = 0; r < 24; ++r) {
        float v = (lane < 54) ? xs[r * 54 + lane] : 1.0f;
        uint64_t mk = __ballot(v < 0.0f);
        if (lane == 0) s_rows[wv][r] = mk;
    }
    __syncthreads();

    // phase 2: conv1 via LUT
    for (int i = tid; i < 4 * 286; i += 256) {
        int sl = i / 286, p = i - sl * 286;
        int oy = p / 26, ox = p - oy * 26;
        uint64_t r0 = s_rows[sl][2 * oy];
        uint64_t r1 = s_rows[sl][2 * oy + 1];
        uint64_t r2 = s_rows[sl][2 * oy + 2];
        int sh = 2 * ox;
        uint32_t px = ((uint32_t)(r0 >> sh) & 7u)
                    | (((uint32_t)(r1 >> sh) & 7u) << 3)
                    | (((uint32_t)(r2 >> sh) & 7u) << 6);
        s_in[sl][p] = s_lut[px];
    }
    __syncthreads();

    // phase 3: wave wv -> sample s; lane = output position
    int p  = (lane < 60) ? lane : 59;
    int oy = p / 12, ox = p - 12 * oy;
    uint32_t t[9];
    #pragma unroll
    for (int ky = 0; ky < 3; ++ky) {
        const uint32_t* rp = &s_in[wv][(2 * oy + ky) * 26 + 2 * ox];
        t[ky * 3 + 0] = rp[0];
        t[ky * 3 + 1] = rp[1];
        t[ky * 3 + 2] = rp[2];
    }
    int B = 0;
    #pragma unroll
    for (int q = 0; q < 9; ++q) B += __popc(t[q]);
    int nB = -B;

    uint32_t w0 = 0, w1 = 0;
    #pragma unroll 4
    for (int c = 0; c < 64; ++c) {
        const uint32_t* cd = cdat + c * 10;   // wave-uniform -> s_load
        int P = 0;
        #pragma unroll
        for (int q = 0; q < 9; ++q) P += __popc(t[q] & cd[q]);
        int v = 2 * P + nB;
        uint64_t mk = __ballot(v >= (int)cd[9]);
        if (lane == c) {
            w0 = (uint32_t)mk;
            w1 = (uint32_t)(mk >> 32) & 0x0FFFFFFFu;   // drop dup lanes 60..63
        }
    }

    int bsum = __popc(w0) + __popc(w1);
    #pragma unroll
    for (int off = 32; off > 0; off >>= 1) bsum += __shfl_xor(bsum, off, 64);
    if (lane == 0) Bs[s] = bsum;

    *(uint2*)(h2b + (size_t)s * 128 + 2 * lane) = make_uint2(w0, w1);
}

// ---------------------------------------------------------------------------
// lin kernel: weight tile in LDS (32 KB, prebuilt layout), lane = j.
// Activations via wave-uniform s_load_dwordx4; 16 samples/wave.
// grid: 1024 blocks. XCD-aware map: jw = blockIdx>>7, chunk = blockIdx&127,
// so the 8 jw-blocks sharing a chunk are {c, c+128, ...} == c (mod 8) ->
// same XCD -> chunk activations fetched from HBM once, then L2-hit.
// (R5 map put them on 8 different XCDs: FETCH_SIZE 33 MB = 8x h2b.)
// ---------------------------------------------------------------------------
__global__ __launch_bounds__(256) void lin_kernel(
    const uint32_t* __restrict__ h2b,
    const uint32_t* __restrict__ wlin4,
    const int* __restrict__ Tlin,
    const int* __restrict__ Bs,
    uint64_t* __restrict__ h3)
{
    __shared__ uint4 s_w[2048];          // [kq*64 + j] : 32 KB

    int tid  = threadIdx.x;
    int lane = tid & 63;
    int wv   = __builtin_amdgcn_readfirstlane((int)(tid >> 6));
    int jw    = blockIdx.x >> 7;         // 0..7  (XCD-locality map)
    int chunk = blockIdx.x & 127;        // 0..127

    const uint4* wsrc = (const uint4*)wlin4 + (size_t)jw * 2048;
    #pragma unroll
    for (int i = 0; i < 8; ++i)
        s_w[i * 256 + tid] = wsrc[i * 256 + tid];

    int j = jw * 64 + lane;
    int T = Tlin[j];
    int sbase = chunk * 64 + wv * 16;
    __syncthreads();

    int P[16];
    #pragma unroll
    for (int i = 0; i < 16; ++i) P[i] = 0;

    for (int kq = 0; kq < 32; ++kq) {
        uint4 w4 = s_w[kq * 64 + lane];
        const uint4* abase = (const uint4*)(h2b + (size_t)sbase * 128) + kq;
        #pragma unroll
        for (int i = 0; i < 16; ++i) {
            uint4 a = abase[i * 32];                 // wave-uniform -> s_load
            P[i] += __popc(a.x & w4.x);
            P[i] += __popc(a.y & w4.y);
            P[i] += __popc(a.z & w4.z);
            P[i] += __popc(a.w & w4.w);
        }
    }

    #pragma unroll
    for (int i = 0; i < 16; ++i) {
        int s = sbase + i;
        int v = 2 * P[i] - Bs[s];
        uint64_t mk = __ballot(v >= T);
        if (lane == 0) h3[(size_t)jw * NB + s] = mk;
    }
}

// ---------------------------------------------------------------------------
// out kernel: thread -> (o, s); o uniform per block -> wout scalar loads.
// ---------------------------------------------------------------------------
__global__ __launch_bounds__(256) void out_kernel(
    const uint64_t* __restrict__ h3,
    const uint32_t* __restrict__ wout,
    const float* __restrict__ out_b,
    float* __restrict__ out)
{
    int gidx = blockIdx.x * 256 + threadIdx.x;   // 0..81919
    int o = gidx >> 13;
    int s = gidx & 8191;
    const uint64_t* wo = (const uint64_t*)wout + o * 8;
    int P = 0, B = 0;
    #pragma unroll
    for (int k = 0; k < 8; ++k) {
        uint64_t a = h3[(size_t)k * NB + s];
        P += __popcll(a & wo[k]);
        B += __popcll(a);
    }
    out[(size_t)s * 10 + o] = __fadd_rn((float)(2 * P - B), out_b[o]);
}

// ---------------------------------------------------------------------------
extern "C" void kernel_launch(void* const* d_in, const int* in_sizes, int n_in,
                              void* d_out, int out_size, void* d_ws, size_t ws_size,
                              hipStream_t stream)
{
    const float* x       = (const float*)d_in[0];
    const float* conv1_w = (const float*)d_in[1];
    const float* conv1_b = (const float*)d_in[2];
    const float* bn1_g   = (const float*)d_in[3];
    const float* bn1_b   = (const float*)d_in[4];
    const float* bn1_m   = (const float*)d_in[5];
    const float* bn1_v   = (const float*)d_in[6];
    const float* conv2_w = (const float*)d_in[7];
    const float* conv2_b = (const float*)d_in[8];
    const float* bn2_g   = (const float*)d_in[9];
    const float* bn2_b   = (const float*)d_in[10];
    const float* bn2_m   = (const float*)d_in[11];
    const float* bn2_v   = (const float*)d_in[12];
    const float* lin_w   = (const float*)d_in[13];
    const float* lin_b   = (const float*)d_in[14];
    const float* out_w   = (const float*)d_in[15];
    const float* out_b   = (const float*)d_in[16];

    char* ws = (char*)d_ws;
    uint32_t* h2b   = (uint32_t*)(ws + 0);
    uint64_t* h3    = (uint64_t*)(ws + 4194304);
    uint32_t* wlin4 = (uint32_t*)(ws + 4718592);
    uint32_t* cdat  = (uint32_t*)(ws + 4980736);
    uint32_t* lut   = (uint32_t*)(ws + 4983296);
    uint32_t* wout  = (uint32_t*)(ws + 4985344);
    int*      Tlin  = (int*)     (ws + 4985984);
    int*      Bs    = (int*)     (ws + 4988032);

    pack_kernel<<<508, 256, 0, stream>>>(conv1_w, conv1_b, conv2_w, conv2_b,
                                         lin_w, lin_b, out_w,
                                         bn1_g, bn1_b, bn1_m, bn1_v,
                                         bn2_g, bn2_b, bn2_m, bn2_v,
                                         wlin4, cdat, lut, wout, Tlin);
    conv_kernel<<<NB / 4, 256, 0, stream>>>(x, cdat, lut, h2b, Bs);
    lin_kernel<<<1024, 256, 0, stream>>>(h2b, wlin4, Tlin, Bs, h3);
    out_kernel<<<320, 256, 0, stream>>>(h3, wout, out_b, (float*)d_out);
}